// Round 1
// baseline (134.212 us; speedup 1.0000x reference)
//
#include <hip/hip_runtime.h>

// SimpleRelativeAttention collapses: einsum 'bnqk,bnqe->bnqe' multiplies v by
// softmax row-sums (==1), so attention is an identity on v.
// out = (x @ Wv + b_v) @ W_proj + b_proj, Wv = w_qkv[:, 2048:3072].

#define DIMC 1024
#define MTOT 4096   // BATCH * SEQ

__device__ __forceinline__ unsigned short f2bf(float f) {
  unsigned u = __float_as_uint(f);
  u += 0x7FFFu + ((u >> 16) & 1u);   // round-to-nearest-even
  return (unsigned short)(u >> 16);
}

typedef __attribute__((ext_vector_type(8))) short short8;
typedef __attribute__((ext_vector_type(4))) float floatx4;

__device__ __forceinline__ void async_copy16(const unsigned short* g, unsigned short* l) {
  __builtin_amdgcn_global_load_lds(
      (const __attribute__((address_space(1))) unsigned int*)g,
      (__attribute__((address_space(3))) unsigned int*)l,
      16, 0, 0);
}

// fp32 -> bf16 elementwise, 4 elems/thread
__global__ void cast_bf16_kernel(const float* __restrict__ in,
                                 unsigned short* __restrict__ out) {
  int i = (blockIdx.x * 256 + threadIdx.x) * 4;
  float4 f = *(const float4*)(in + i);
  ushort4 o;
  o.x = f2bf(f.x); o.y = f2bf(f.y); o.z = f2bf(f.z); o.w = f2bf(f.w);
  *(ushort4*)(out + i) = o;
}

// out[n][k] = in[k*stride + col0 + n]; out is [DIMC][DIMC] bf16 row-major
__global__ void transpose_cast_kernel(const float* __restrict__ in, int stride,
                                      int col0, unsigned short* __restrict__ out) {
  __shared__ float tile[32][33];
  const int t = threadIdx.x;
  const int tx = t & 31, ty = t >> 5;
  const int bx = blockIdx.x, by = blockIdx.y;
#pragma unroll
  for (int r = 0; r < 4; ++r) {
    int kl = ty + r * 8;
    tile[kl][tx] = in[(size_t)(by * 32 + kl) * stride + col0 + bx * 32 + tx];
  }
  __syncthreads();
#pragma unroll
  for (int r = 0; r < 4; ++r) {
    int nl = ty + r * 8;
    out[(size_t)(bx * 32 + nl) * DIMC + by * 32 + tx] = f2bf(tile[tx][nl]);
  }
}

// C[M,N] = A[M,K] @ Bt[N,K]^T + bias[N]
// 64x128 block tile, BK=32, 256 threads = 4 waves, each wave 64x32 (4x2 frags)
template <bool BF16_OUT>
__global__ __launch_bounds__(256, 2) void gemm_bt_kernel(
    const unsigned short* __restrict__ A,   // [M,K] bf16
    const unsigned short* __restrict__ Bt,  // [N,K] bf16
    const float* __restrict__ bias,         // [N]
    void* __restrict__ Cout, int M, int N, int K) {
  __shared__ __align__(16) unsigned short As[64 * 32];
  __shared__ __align__(16) unsigned short Bs[128 * 32];
  const int tid = threadIdx.x;
  const int wv = tid >> 6;
  const int lane = tid & 63;
  const int m0 = blockIdx.y * 64;
  const int n0 = blockIdx.x * 128;

  floatx4 acc[4][2] = {};

  // staging: chunk = 16B = 8 bf16; A tile = 256 chunks (1/thread), B = 512 (2/thread)
  const int arow = tid >> 2;
  const int aoff = (tid & 3) * 8;
  const unsigned short* Ag  = A  + (size_t)(m0 + arow) * K + aoff;
  const unsigned short* Bg0 = Bt + (size_t)(n0 + arow) * K + aoff;
  const unsigned short* Bg1 = Bt + (size_t)(n0 + 64 + arow) * K + aoff;
  unsigned short* AsW  = As + wv * 512;          // HW adds lane*16B
  unsigned short* BsW0 = Bs + wv * 512;
  unsigned short* BsW1 = Bs + 2048 + wv * 512;

  const int lr = lane & 15;
  const int qr = lane >> 4;

  for (int k0 = 0; k0 < K; k0 += 32) {
    async_copy16(Ag + k0, AsW);
    async_copy16(Bg0 + k0, BsW0);
    async_copy16(Bg1 + k0, BsW1);
    __syncthreads();   // compiler emits vmcnt(0) drain before s_barrier

    short8 a[4], b[2];
#pragma unroll
    for (int mi = 0; mi < 4; ++mi)
      a[mi] = *(const short8*)(As + (mi * 16 + lr) * 32 + qr * 8);
#pragma unroll
    for (int ni = 0; ni < 2; ++ni)
      b[ni] = *(const short8*)(Bs + (wv * 32 + ni * 16 + lr) * 32 + qr * 8);
#pragma unroll
    for (int mi = 0; mi < 4; ++mi)
#pragma unroll
      for (int ni = 0; ni < 2; ++ni)
        acc[mi][ni] = __builtin_amdgcn_mfma_f32_16x16x32_bf16(a[mi], b[ni],
                                                              acc[mi][ni], 0, 0, 0);
    __syncthreads();
  }

  // epilogue: C row = m0+mi*16+qr*4+r, col = n0+wv*32+ni*16+lr
#pragma unroll
  for (int mi = 0; mi < 4; ++mi) {
#pragma unroll
    for (int ni = 0; ni < 2; ++ni) {
      const int col = n0 + wv * 32 + ni * 16 + lr;
      const float bv = bias[col];
#pragma unroll
      for (int r = 0; r < 4; ++r) {
        const int row = m0 + mi * 16 + qr * 4 + r;
        const float val = acc[mi][ni][r] + bv;
        if (BF16_OUT)
          ((unsigned short*)Cout)[(size_t)row * N + col] = f2bf(val);
        else
          ((float*)Cout)[(size_t)row * N + col] = val;
      }
    }
  }
}

extern "C" void kernel_launch(void* const* d_in, const int* in_sizes, int n_in,
                              void* d_out, int out_size, void* d_ws, size_t ws_size,
                              hipStream_t stream) {
  const float* x      = (const float*)d_in[0];  // [4,1024,1024]
  const float* w_qkv  = (const float*)d_in[1];  // [1024,3072]
  const float* b_qkv  = (const float*)d_in[2];  // [3072]
  const float* w_proj = (const float*)d_in[3];  // [1024,1024]
  const float* b_proj = (const float*)d_in[4];  // [1024]
  // d_in[5]=rel_table, d_in[6]=rel_index: unused — softmax rows sum to 1,
  // so the attention block is an identity on v (see header comment).
  float* out = (float*)d_out;

  char* ws = (char*)d_ws;
  unsigned short* xb  = (unsigned short*)(ws);                       // 8 MB [4096,1024]
  unsigned short* WvT = (unsigned short*)(ws + (size_t)(8u << 20));  // 2 MB [1024,1024]
  unsigned short* WpT = (unsigned short*)(ws + (size_t)(10u << 20)); // 2 MB
  unsigned short* vb  = (unsigned short*)(ws + (size_t)(12u << 20)); // 8 MB [4096,1024]

  // 1. x -> bf16
  cast_bf16_kernel<<<(MTOT * DIMC) / (256 * 4), 256, 0, stream>>>(x, xb);
  // 2. transpose+cast weights: WvT[n][k] = w_qkv[k][2048+n]; WpT[n][k] = w_proj[k][n]
  transpose_cast_kernel<<<dim3(32, 32), 256, 0, stream>>>(w_qkv, 3 * DIMC, 2 * DIMC, WvT);
  transpose_cast_kernel<<<dim3(32, 32), 256, 0, stream>>>(w_proj, DIMC, 0, WpT);
  // 3. v = x @ Wv + b_v  (bf16 out)
  gemm_bt_kernel<true><<<dim3(DIMC / 128, MTOT / 64), 256, 0, stream>>>(
      xb, WvT, b_qkv + 2 * DIMC, vb, MTOT, DIMC, DIMC);
  // 4. out = v @ W_proj + b_proj  (fp32 out)
  gemm_bt_kernel<false><<<dim3(DIMC / 128, MTOT / 64), 256, 0, stream>>>(
      vb, WpT, b_proj, out, MTOT, DIMC, DIMC);
}